// Round 10
// baseline (331.575 us; speedup 1.0000x reference)
//
#include <hip/hip_runtime.h>

#define NT 256
#define CHUNK 1024
#define PBLK2 2048  // blocks for hist/partition passes
#define PTILE 4096  // staged partition tile (edges)

static inline int nbi(long long n) { return (int)((n + NT - 1) / NT); }

// ===================== bucket-partition CSR build =====================
// buckets of 256 nodes: bucket = dst >> 8, d_local = dst & 255
// packed entry = (d_local << 17) | src   (requires N <= 131072)

__global__ __launch_bounds__(256) void k_histB(const int* __restrict__ dst,
                                               int* __restrict__ histB,
                                               int E, int NB) {
    __shared__ int lh[512];
    int t = threadIdx.x;
    for (int i = t; i < 512; i += 256) lh[i] = 0;
    __syncthreads();
    int chunk = (E + gridDim.x - 1) / gridDim.x;
    int lo = blockIdx.x * chunk, hi = min(E, lo + chunk);
    for (int i = lo + t; i < hi; i += 256)
        atomicAdd(&lh[dst[i] >> 8], 1);
    __syncthreads();
    for (int b = t; b < NB; b += 256)
        histB[(size_t)blockIdx.x * NB + b] = lh[b];
}

__global__ __launch_bounds__(256) void k_scanB2(const int* __restrict__ histB,
                                                int* __restrict__ cursorT,
                                                int* __restrict__ tot,
                                                int NB, int nblk) {
    __shared__ int ch[256];
    __shared__ int carry;
    int b = blockIdx.x, t = threadIdx.x;
    if (t == 0) carry = 0;
    __syncthreads();
    for (int c = 0; c < nblk; c += 256) {
        int blk = c + t;
        int v = (blk < nblk) ? histB[(size_t)blk * NB + b] : 0;
        ch[t] = v;
        __syncthreads();
        for (int o = 1; o < 256; o <<= 1) {
            int x = (t >= o) ? ch[t - o] : 0;
            __syncthreads();
            ch[t] += x;
            __syncthreads();
        }
        int excl = ch[t] - v + carry;
        if (blk < nblk) cursorT[(size_t)b * PBLK2 + blk] = excl;
        __syncthreads();
        if (t == 0) carry += ch[255];
        __syncthreads();
    }
    if (t == 0) tot[b] = carry;
}

__global__ __launch_bounds__(512) void k_bscan(const int* __restrict__ hist_g,
                                               int* __restrict__ bbase,
                                               int* __restrict__ rowst,
                                               int NB, int N, int E) {
    __shared__ int s[512];
    int t = threadIdx.x;
    int own = (t < NB) ? hist_g[t] : 0;
    s[t] = own;
    __syncthreads();
    for (int o = 1; o < 512; o <<= 1) {
        int v = (t >= o) ? s[t - o] : 0;
        __syncthreads();
        s[t] += v;
        __syncthreads();
    }
    if (t < NB) bbase[t] = s[t] - own;
    if (t == 0) { bbase[NB] = E; rowst[N] = E; }
}

// single-tile partition: hist comes from histB (no per-edge recount)
__global__ __launch_bounds__(256) void k_partF(const int* __restrict__ src,
                                               const int* __restrict__ dst,
                                               const int* __restrict__ bbase,
                                               const int* __restrict__ histB,
                                               const int* __restrict__ cursorT,
                                               int* __restrict__ part,
                                               int E, int NB) {
    __shared__ int wadj[512], tloff[512], tcnt[512], ps[256];
    __shared__ int stage[PTILE];
    __shared__ unsigned short sbkt[PTILE];
    int t = threadIdx.x;
    int blk = blockIdx.x;
    int chunk = (E + gridDim.x - 1) / gridDim.x;
    int lo = blk * chunk, hi = min(E, lo + chunk);
    if (lo >= hi) return;
    int cnt = hi - lo;
    int b0 = 2 * t, b1 = 2 * t + 1;
    int v0c = (b0 < NB) ? histB[(size_t)blk * NB + b0] : 0;
    int v1c = (b1 < NB) ? histB[(size_t)blk * NB + b1] : 0;
    ps[t] = v0c + v1c;
    __syncthreads();
    for (int o = 1; o < 256; o <<= 1) {
        int v = (t >= o) ? ps[t - o] : 0;
        __syncthreads();
        ps[t] += v;
        __syncthreads();
    }
    int excl = ps[t] - v0c - v1c;
    tloff[b0] = excl;
    tloff[b1] = excl + v0c;
    tcnt[b0] = 0; tcnt[b1] = 0;
    if (b0 < NB) wadj[b0] = bbase[b0] + cursorT[(size_t)b0 * PBLK2 + blk] - excl;
    if (b1 < NB) wadj[b1] = bbase[b1] + cursorT[(size_t)b1 * PBLK2 + blk] - (excl + v0c);
    __syncthreads();
    for (int i = lo + t; i < hi; i += 256) {
        int d = dst[i], s = src[i];
        int b = d >> 8;
        int pos = tloff[b] + atomicAdd(&tcnt[b], 1);
        stage[pos] = ((d & 255) << 17) | s;
        sbkt[pos] = (unsigned short)b;
    }
    __syncthreads();
    for (int i = t; i < cnt; i += 256) {
        int b = sbkt[i];
        part[wadj[b] + i] = stage[i];
    }
}

// one block/bucket: LDS count -> scan -> rowst/dis/v0 -> place csr
__global__ __launch_bounds__(512) void k_build(const int* __restrict__ bbase,
                                               const int* __restrict__ part,
                                               const float* __restrict__ x,
                                               int* __restrict__ rowst,
                                               float* __restrict__ dis,
                                               float* __restrict__ v0,
                                               int* __restrict__ csr,
                                               int N) {
    __shared__ int dcnt[256], doff[256];
    int b = blockIdx.x, t = threadIdx.x;
    int lo = bbase[b], hi = bbase[b + 1];
    if (t < 256) dcnt[t] = 0;
    __syncthreads();
    for (int i = lo + t; i < hi; i += 512)
        atomicAdd(&dcnt[part[i] >> 17], 1);
    __syncthreads();
    int own = 0;
    if (t < 256) { own = dcnt[t]; doff[t] = own; }
    __syncthreads();
    for (int o = 1; o < 256; o <<= 1) {
        int v = 0;
        if (t < 256 && t >= o) v = doff[t - o];
        __syncthreads();
        if (t < 256) doff[t] += v;
        __syncthreads();
    }
    if (t < 256) {
        int excl = doff[t] - own;
        int node = (b << 8) + t;
        if (node < N) {
            rowst[node] = lo + excl;
            float dn = rsqrtf((float)own + 1.0f);
            dis[node] = dn;
            float2 xv = *reinterpret_cast<const float2*>(x + 2 * node);
            *reinterpret_cast<float2*>(v0 + 2 * node) = make_float2(dn * xv.x, dn * xv.y);
        }
        dcnt[t] = excl;
    }
    __syncthreads();
    for (int i = lo + t; i < hi; i += 512) {
        int pv = part[i];
        int slot = atomicAdd(&dcnt[pv >> 17], 1);
        csr[lo + slot] = pv & 0x1FFFF;
    }
}

// ===================== gather kernels =====================

// pass 1: gather 2-wide v0 (8 lanes/node); epilogue W0,b0 then W1 -> u1
__global__ __launch_bounds__(NT) void k_gL1(const int* __restrict__ rowst,
                                            const int* __restrict__ csr,
                                            const float* __restrict__ dis,
                                            const float* __restrict__ v0,
                                            const float* __restrict__ W0,
                                            const float* __restrict__ b0,
                                            const float* __restrict__ W1,
                                            float* __restrict__ un, int N) {
    int g = blockIdx.x * NT + threadIdx.x;
    int n = g >> 3, sub = g & 7;
    if (n >= N) return;
    int base = rowst[n], end = rowst[n + 1];
    int i = base + sub;
    float ax = 0.0f, ay = 0.0f;
    int idx[8];
#pragma unroll
    for (int k = 0; k < 8; ++k) {
        int j = i + 8 * k;
        idx[k] = (j < end) ? csr[j] : -1;
    }
    float2 vv[8];
#pragma unroll
    for (int k = 0; k < 8; ++k) {
        int s = idx[k] >= 0 ? idx[k] : n;
        vv[k] = *reinterpret_cast<const float2*>(v0 + 2 * s);
    }
#pragma unroll
    for (int k = 0; k < 8; ++k) {
        if (idx[k] >= 0) { ax += vv[k].x; ay += vv[k].y; }
    }
    for (int j = base + 64 + sub; j < end; j += 8) {
        int s = csr[j];
        float2 p = *reinterpret_cast<const float2*>(v0 + 2 * s);
        ax += p.x; ay += p.y;
    }
    ax += __shfl_xor(ax, 1, 64); ax += __shfl_xor(ax, 2, 64); ax += __shfl_xor(ax, 4, 64);
    ay += __shfl_xor(ay, 1, 64); ay += __shfl_xor(ay, 2, 64); ay += __shfl_xor(ay, 4, 64);
    float2 sv = *reinterpret_cast<const float2*>(v0 + 2 * n);
    ax += sv.x; ay += sv.y;
    float dn = dis[n];
    float gg = dn * (ax * W0[sub] + ay * W0[8 + sub]) + b0[sub];
    float h = gg > 0.0f ? gg : expm1f(gg);
    int lb = (threadIdx.x & 63) & ~7;
    float o = 0.0f;
#pragma unroll
    for (int k = 0; k < 8; ++k) o += __shfl(h, lb + k, 64) * W1[k * 8 + sub];
    un[8 * n + sub] = dn * o;
}

// mid pass: 8 lanes/node, lane pairs share an edge (half=sub&1, eslot=sub>>1);
// each lane loads ONE float4 per edge -> paired same-line loads coalesce.
__global__ __launch_bounds__(NT) void k_gL8(const int* __restrict__ rowst,
                                            const int* __restrict__ csr,
                                            const float* __restrict__ dis,
                                            const float* __restrict__ u,
                                            const float* __restrict__ b,
                                            const float* __restrict__ W,
                                            float* __restrict__ un, int N) {
    int g = blockIdx.x * NT + threadIdx.x;
    int n = g >> 3, sub = g & 7;
    if (n >= N) return;
    int half = sub & 1, eslot = sub >> 1;
    int base = rowst[n], end = rowst[n + 1];
    float a[4];
#pragma unroll
    for (int f = 0; f < 4; ++f) a[f] = 0.0f;
    int idx[16];
#pragma unroll
    for (int k = 0; k < 16; ++k) {
        int j = base + 4 * k + eslot;
        idx[k] = (j < end) ? csr[j] : -1;
    }
    float4 vv[16];
#pragma unroll
    for (int k = 0; k < 16; ++k) {
        int s = idx[k] >= 0 ? idx[k] : n;
        vv[k] = *reinterpret_cast<const float4*>(u + 8 * s + 4 * half);
    }
#pragma unroll
    for (int k = 0; k < 16; ++k) {
        if (idx[k] >= 0) {
            a[0] += vv[k].x; a[1] += vv[k].y; a[2] += vv[k].z; a[3] += vv[k].w;
        }
    }
    for (int j = base + 64 + eslot; j < end; j += 4) {
        int s = csr[j];
        float4 p = *reinterpret_cast<const float4*>(u + 8 * s + 4 * half);
        a[0] += p.x; a[1] += p.y; a[2] += p.z; a[3] += p.w;
    }
    if (eslot == 0) {
        float4 sv = *reinterpret_cast<const float4*>(u + 8 * n + 4 * half);
        a[0] += sv.x; a[1] += sv.y; a[2] += sv.z; a[3] += sv.w;
    }
#pragma unroll
    for (int f = 0; f < 4; ++f) {
        a[f] += __shfl_xor(a[f], 2, 64);
        a[f] += __shfl_xor(a[f], 4, 64);
    }
    float dn = dis[n];
    float h[4];
#pragma unroll
    for (int f = 0; f < 4; ++f) {
        float gg = a[f] * dn + b[4 * half + f];
        h[f] = gg > 0.0f ? gg : expm1f(gg);
    }
    int lb = (threadIdx.x & 63) & ~7;
    float o = 0.0f;
#pragma unroll
    for (int f = 0; f < 4; ++f) {
        o += __shfl(h[f], lb + 0, 64) * W[f * 8 + sub];
        o += __shfl(h[f], lb + 1, 64) * W[(4 + f) * 8 + sub];
    }
    un[8 * n + sub] = dn * o;
}

// head pass: same paired-lane gather; epilogue b3+elu then Wv/Wp -> uH (2-wide)
__global__ __launch_bounds__(NT) void k_gHead(const int* __restrict__ rowst,
                                              const int* __restrict__ csr,
                                              const float* __restrict__ dis,
                                              const float* __restrict__ u,
                                              const float* __restrict__ b,
                                              const float* __restrict__ Wv,
                                              const float* __restrict__ Wp,
                                              float* __restrict__ uH, int N) {
    int g = blockIdx.x * NT + threadIdx.x;
    int n = g >> 3, sub = g & 7;
    if (n >= N) return;
    int half = sub & 1, eslot = sub >> 1;
    int base = rowst[n], end = rowst[n + 1];
    float a[4];
#pragma unroll
    for (int f = 0; f < 4; ++f) a[f] = 0.0f;
    int idx[16];
#pragma unroll
    for (int k = 0; k < 16; ++k) {
        int j = base + 4 * k + eslot;
        idx[k] = (j < end) ? csr[j] : -1;
    }
    float4 vv[16];
#pragma unroll
    for (int k = 0; k < 16; ++k) {
        int s = idx[k] >= 0 ? idx[k] : n;
        vv[k] = *reinterpret_cast<const float4*>(u + 8 * s + 4 * half);
    }
#pragma unroll
    for (int k = 0; k < 16; ++k) {
        if (idx[k] >= 0) {
            a[0] += vv[k].x; a[1] += vv[k].y; a[2] += vv[k].z; a[3] += vv[k].w;
        }
    }
    for (int j = base + 64 + eslot; j < end; j += 4) {
        int s = csr[j];
        float4 p = *reinterpret_cast<const float4*>(u + 8 * s + 4 * half);
        a[0] += p.x; a[1] += p.y; a[2] += p.z; a[3] += p.w;
    }
    if (eslot == 0) {
        float4 sv = *reinterpret_cast<const float4*>(u + 8 * n + 4 * half);
        a[0] += sv.x; a[1] += sv.y; a[2] += sv.z; a[3] += sv.w;
    }
#pragma unroll
    for (int f = 0; f < 4; ++f) {
        a[f] += __shfl_xor(a[f], 2, 64);
        a[f] += __shfl_xor(a[f], 4, 64);
    }
    float dn = dis[n];
    float tv = 0.0f, tp = 0.0f;
#pragma unroll
    for (int f = 0; f < 4; ++f) {
        float gg = a[f] * dn + b[4 * half + f];
        float h = gg > 0.0f ? gg : expm1f(gg);
        tv += h * Wv[4 * half + f];
        tp += h * Wp[4 * half + f];
    }
    tv += __shfl_xor(tv, 1, 64);
    tp += __shfl_xor(tp, 1, 64);
    if (sub == 0)
        *reinterpret_cast<float2*>(uH + 2 * n) = make_float2(dn * tv, dn * tp);
}

// final: gather 2-wide uH -> proba out + value reduce
__global__ __launch_bounds__(NT) void k_g2F(const int* __restrict__ rowst,
                                            const int* __restrict__ csr,
                                            const float* __restrict__ dis,
                                            const float* __restrict__ uH,
                                            const float* __restrict__ bp,
                                            float* __restrict__ out,
                                            float* __restrict__ vsum, int N) {
    int g = blockIdx.x * NT + threadIdx.x;
    int n = g >> 3, sub = g & 7;
    bool valid = n < N;
    float av = 0.0f, ap = 0.0f;
    if (valid) {
        int base = rowst[n], end = rowst[n + 1];
        int i = base + sub;
        int idx[8];
#pragma unroll
        for (int k = 0; k < 8; ++k) {
            int j = i + 8 * k;
            idx[k] = (j < end) ? csr[j] : -1;
        }
        float2 vv[8];
#pragma unroll
        for (int k = 0; k < 8; ++k) {
            int s = idx[k] >= 0 ? idx[k] : n;
            vv[k] = *reinterpret_cast<const float2*>(uH + 2 * s);
        }
#pragma unroll
        for (int k = 0; k < 8; ++k) {
            if (idx[k] >= 0) { av += vv[k].x; ap += vv[k].y; }
        }
        for (int j = base + 64 + sub; j < end; j += 8) {
            int s = csr[j];
            float2 p = *reinterpret_cast<const float2*>(uH + 2 * s);
            av += p.x; ap += p.y;
        }
    }
    av += __shfl_xor(av, 1, 64); av += __shfl_xor(av, 2, 64); av += __shfl_xor(av, 4, 64);
    ap += __shfl_xor(ap, 1, 64); ap += __shfl_xor(ap, 2, 64); ap += __shfl_xor(ap, 4, 64);
    float contrib = 0.0f;
    if (valid && sub == 0) {
        float2 selfv = *reinterpret_cast<const float2*>(uH + 2 * n);
        av += selfv.x; ap += selfv.y;
        float dn = dis[n];
        out[n] = ap * dn + bp[0];
        contrib = av * dn;
    }
#pragma unroll
    for (int o = 32; o > 0; o >>= 1) contrib += __shfl_down(contrib, o, 64);
    __shared__ float sred[NT / 64];
    if ((threadIdx.x & 63) == 0) sred[threadIdx.x >> 6] = contrib;
    __syncthreads();
    if (threadIdx.x == 0) {
        float bsum = 0.0f;
#pragma unroll
        for (int k = 0; k < NT / 64; ++k) bsum += sred[k];
        atomicAdd(vsum, bsum);
    }
}

__global__ void k_final(const float* __restrict__ vsum,
                        const float* __restrict__ bv,
                        float* __restrict__ out, int N) {
    out[0] = vsum[0] * (1.0f / (float)N) + bv[0];
}

// ============== fallback: two-pass exact-CSR build ==============

__global__ __launch_bounds__(NT) void k_count(const int* __restrict__ dst,
                                              int* __restrict__ deg, int E) {
    int e = blockIdx.x * NT + threadIdx.x;
    if (e < E) atomicAdd(&deg[dst[e]], 1);
}

__global__ __launch_bounds__(NT) void k_scanA(const int* __restrict__ deg,
                                              int* __restrict__ partial, int N) {
    int t = threadIdx.x;
    int base = blockIdx.x * CHUNK + t * 4;
    int s = 0;
#pragma unroll
    for (int j = 0; j < 4; ++j) { int i = base + j; if (i < N) s += deg[i]; }
    __shared__ int red[NT];
    red[t] = s; __syncthreads();
    for (int o = NT / 2; o > 0; o >>= 1) {
        if (t < o) red[t] += red[t + o];
        __syncthreads();
    }
    if (t == 0) partial[blockIdx.x] = red[0];
}

__global__ void k_scanB(const int* __restrict__ partial, int* __restrict__ chunkoff,
                        int* __restrict__ rowst, int nblk, int N) {
    if (threadIdx.x == 0) {
        int off = 0;
        for (int b = 0; b < nblk; ++b) { chunkoff[b] = off; off += partial[b]; }
        rowst[N] = off;
    }
}

__global__ __launch_bounds__(NT) void k_scanC(const int* __restrict__ deg,
                                              const int* __restrict__ chunkoff,
                                              int* __restrict__ rowst,
                                              float* __restrict__ dis, int N) {
    int t = threadIdx.x;
    int base = blockIdx.x * CHUNK + t * 4;
    int v[4]; int tsum = 0;
#pragma unroll
    for (int j = 0; j < 4; ++j) { int i = base + j; v[j] = (i < N) ? deg[i] : 0; tsum += v[j]; }
    __shared__ int ss[NT];
    ss[t] = tsum; __syncthreads();
    for (int o = 1; o < NT; o <<= 1) {
        int x = (t >= o) ? ss[t - o] : 0;
        __syncthreads();
        ss[t] += x;
        __syncthreads();
    }
    int run = ss[t] - tsum + chunkoff[blockIdx.x];
#pragma unroll
    for (int j = 0; j < 4; ++j) {
        int i = base + j;
        if (i < N) { rowst[i] = run; dis[i] = rsqrtf((float)v[j] + 1.0f); run += v[j]; }
    }
}

__global__ __launch_bounds__(NT) void k_fill(const int* __restrict__ src,
                                             const int* __restrict__ dst,
                                             const int* __restrict__ rowst,
                                             int* __restrict__ deg,
                                             int* __restrict__ csr, int E) {
    int e = blockIdx.x * NT + threadIdx.x;
    if (e >= E) return;
    int s = src[e], d = dst[e];
    int old = atomicSub(&deg[d], 1);
    csr[rowst[d] + old - 1] = s;
}

__global__ __launch_bounds__(NT) void k_v0(const float* __restrict__ x,
                                           const float* __restrict__ dis,
                                           float* __restrict__ v0, int N) {
    int n = blockIdx.x * NT + threadIdx.x;
    if (n >= N) return;
    float dn = dis[n];
    float2 xv = *reinterpret_cast<const float2*>(x + 2 * n);
    *reinterpret_cast<float2*>(v0 + 2 * n) = make_float2(dn * xv.x, dn * xv.y);
}

// ================================ launch ================================

extern "C" void kernel_launch(void* const* d_in, const int* in_sizes, int n_in,
                              void* d_out, int out_size, void* d_ws, size_t ws_size,
                              hipStream_t stream) {
    const float* x  = (const float*)d_in[0];
    const int* ei   = (const int*)d_in[1];
    const float* W0 = (const float*)d_in[2];
    const float* b0 = (const float*)d_in[3];
    const float* W1 = (const float*)d_in[4];
    const float* b1 = (const float*)d_in[5];
    const float* W2 = (const float*)d_in[6];
    const float* b2 = (const float*)d_in[7];
    const float* W3 = (const float*)d_in[8];
    const float* b3 = (const float*)d_in[9];
    const float* Wv = (const float*)d_in[10];
    const float* bv = (const float*)d_in[11];
    const float* Wp = (const float*)d_in[12];
    const float* bp = (const float*)d_in[13];
    float* out = (float*)d_out;

    int N = in_sizes[0] / 2;
    int E = in_sizes[1] / 2;
    const int* src = ei;
    const int* dst = ei + E;
    int NB = (N + 255) >> 8;
    int NP = (N + 3) & ~3;
    int EP = (E + 3) & ~3;
    int chunkP = (E + PBLK2 - 1) / PBLK2;

    size_t needP = ((size_t)22 * NP + 2 * (size_t)EP + 1044) * 4;
    bool histFits = (size_t)2 * PBLK2 * NB <= (size_t)E;

    if (N <= 131072 && NB <= 512 && ws_size >= needP && histFits && chunkP <= PTILE) {
        int* tot    = (int*)d_ws;                   // 512
        int* bbase  = tot + 512;                    // 520 (NB+1 used)
        float* vsum = (float*)(bbase + 520);        // 8
        int* rowst  = (int*)(vsum + 8);             // NP+4 (N+1 used)
        float* dis  = (float*)(rowst + NP + 4);     // NP
        float* v0   = dis + NP;                     // 2NP
        float* uA   = v0 + (size_t)2 * NP;          // 8NP
        float* uB   = uA + (size_t)8 * NP;          // 8NP
        float* uH   = uB + (size_t)8 * NP;          // 2NP
        int* part   = (int*)(uH + (size_t)2 * NP);  // EP
        int* csr    = part + (size_t)EP;            // EP
        int* histB   = csr;                         // scratch inside csr
        int* cursorT = csr + (size_t)PBLK2 * NB;

        hipMemsetAsync(vsum, 0, 4, stream);

        k_histB<<<PBLK2, 256, 0, stream>>>(dst, histB, E, NB);
        k_scanB2<<<NB, 256, 0, stream>>>(histB, cursorT, tot, NB, PBLK2);
        k_bscan<<<1, 512, 0, stream>>>(tot, bbase, rowst, NB, N, E);
        k_partF<<<PBLK2, 256, 0, stream>>>(src, dst, bbase, histB, cursorT, part, E, NB);
        k_build<<<NB, 512, 0, stream>>>(bbase, part, x, rowst, dis, v0, csr, N);

        k_gL1<<<nbi(8LL * N), NT, 0, stream>>>(rowst, csr, dis, v0, W0, b0, W1, uA, N);
        k_gL8<<<nbi(8LL * N), NT, 0, stream>>>(rowst, csr, dis, uA, b1, W2, uB, N);
        k_gL8<<<nbi(8LL * N), NT, 0, stream>>>(rowst, csr, dis, uB, b2, W3, uA, N);
        k_gHead<<<nbi(8LL * N), NT, 0, stream>>>(rowst, csr, dis, uA, b3, Wv, Wp, uH, N);
        k_g2F<<<nbi(8LL * N), NT, 0, stream>>>(rowst, csr, dis, uH, bp, out, vsum, N);
        k_final<<<1, 1, 0, stream>>>(vsum, bv, out + N, N);
    } else {
        // ---- fallback: two-pass exact CSR, same gather kernels ----
        int nblk = (N + CHUNK - 1) / CHUNK;
        int* deg      = (int*)d_ws;                 // N
        int* rowst    = deg + N;                    // N+1
        int* chunkoff = rowst + N + 1;              // nblk
        int* partial  = chunkoff + nblk;            // nblk
        float* dis    = (float*)(partial + nblk);   // N
        float* vsum   = dis + N;                    // 8
        float* v0     = vsum + 8;                   // 2N
        float* uA     = v0 + (size_t)2 * N;         // 8N
        float* uB     = uA + (size_t)8 * N;         // 8N
        float* uH     = uB + (size_t)8 * N;         // 2N
        int* csr      = (int*)(uH + (size_t)2 * N); // E

        hipMemsetAsync(deg, 0, (size_t)N * 4, stream);
        hipMemsetAsync(vsum, 0, 4, stream);

        k_count<<<nbi(E), NT, 0, stream>>>(dst, deg, E);
        k_scanA<<<nblk, NT, 0, stream>>>(deg, partial, N);
        k_scanB<<<1, 64, 0, stream>>>(partial, chunkoff, rowst, nblk, N);
        k_scanC<<<nblk, NT, 0, stream>>>(deg, chunkoff, rowst, dis, N);
        k_fill<<<nbi(E), NT, 0, stream>>>(src, dst, rowst, deg, csr, E);
        k_v0<<<nbi(N), NT, 0, stream>>>(x, dis, v0, N);

        k_gL1<<<nbi(8LL * N), NT, 0, stream>>>(rowst, csr, dis, v0, W0, b0, W1, uA, N);
        k_gL8<<<nbi(8LL * N), NT, 0, stream>>>(rowst, csr, dis, uA, b1, W2, uB, N);
        k_gL8<<<nbi(8LL * N), NT, 0, stream>>>(rowst, csr, dis, uB, b2, W3, uA, N);
        k_gHead<<<nbi(8LL * N), NT, 0, stream>>>(rowst, csr, dis, uA, b3, Wv, Wp, uH, N);
        k_g2F<<<nbi(8LL * N), NT, 0, stream>>>(rowst, csr, dis, uH, bp, out, vsum, N);
        k_final<<<1, 1, 0, stream>>>(vsum, bv, out + N, N);
    }
}

// Round 11
// 324.311 us; speedup vs baseline: 1.0224x; 1.0224x over previous
//
#include <hip/hip_runtime.h>

#define NT 256
#define CHUNK 1024
#define PBLK2 2048  // blocks for hist/partition passes
#define PTILE 4096  // staged partition tile (edges)

static inline int nbi(long long n) { return (int)((n + NT - 1) / NT); }

// ===================== bucket-partition CSR build =====================
// buckets of 256 nodes: bucket = dst >> 8, d_local = dst & 255
// packed entry = (d_local << 17) | src   (requires N <= 131072)

__global__ __launch_bounds__(256) void k_histB(const int* __restrict__ dst,
                                               int* __restrict__ histB,
                                               int E, int NB) {
    __shared__ int lh[512];
    int t = threadIdx.x;
    for (int i = t; i < 512; i += 256) lh[i] = 0;
    __syncthreads();
    int chunk = (E + gridDim.x - 1) / gridDim.x;
    int lo = blockIdx.x * chunk, hi = min(E, lo + chunk);
    for (int i = lo + t; i < hi; i += 256)
        atomicAdd(&lh[dst[i] >> 8], 1);
    __syncthreads();
    for (int b = t; b < NB; b += 256)
        histB[(size_t)blockIdx.x * NB + b] = lh[b];
}

__global__ __launch_bounds__(256) void k_scanB2(const int* __restrict__ histB,
                                                int* __restrict__ cursorT,
                                                int* __restrict__ tot,
                                                int NB, int nblk) {
    __shared__ int ch[256];
    __shared__ int carry;
    int b = blockIdx.x, t = threadIdx.x;
    if (t == 0) carry = 0;
    __syncthreads();
    for (int c = 0; c < nblk; c += 256) {
        int blk = c + t;
        int v = (blk < nblk) ? histB[(size_t)blk * NB + b] : 0;
        ch[t] = v;
        __syncthreads();
        for (int o = 1; o < 256; o <<= 1) {
            int x = (t >= o) ? ch[t - o] : 0;
            __syncthreads();
            ch[t] += x;
            __syncthreads();
        }
        int excl = ch[t] - v + carry;
        if (blk < nblk) cursorT[(size_t)b * PBLK2 + blk] = excl;
        __syncthreads();
        if (t == 0) carry += ch[255];
        __syncthreads();
    }
    if (t == 0) tot[b] = carry;
}

__global__ __launch_bounds__(512) void k_bscan(const int* __restrict__ hist_g,
                                               int* __restrict__ bbase,
                                               int* __restrict__ rowst,
                                               int NB, int N, int E) {
    __shared__ int s[512];
    int t = threadIdx.x;
    int own = (t < NB) ? hist_g[t] : 0;
    s[t] = own;
    __syncthreads();
    for (int o = 1; o < 512; o <<= 1) {
        int v = (t >= o) ? s[t - o] : 0;
        __syncthreads();
        s[t] += v;
        __syncthreads();
    }
    if (t < NB) bbase[t] = s[t] - own;
    if (t == 0) { bbase[NB] = E; rowst[N] = E; }
}

// single-tile partition: hist comes from histB (no per-edge recount)
__global__ __launch_bounds__(256) void k_partF(const int* __restrict__ src,
                                               const int* __restrict__ dst,
                                               const int* __restrict__ bbase,
                                               const int* __restrict__ histB,
                                               const int* __restrict__ cursorT,
                                               int* __restrict__ part,
                                               int E, int NB) {
    __shared__ int wadj[512], tloff[512], tcnt[512], ps[256];
    __shared__ int stage[PTILE];
    __shared__ unsigned short sbkt[PTILE];
    int t = threadIdx.x;
    int blk = blockIdx.x;
    int chunk = (E + gridDim.x - 1) / gridDim.x;
    int lo = blk * chunk, hi = min(E, lo + chunk);
    if (lo >= hi) return;
    int cnt = hi - lo;
    int b0 = 2 * t, b1 = 2 * t + 1;
    int v0c = (b0 < NB) ? histB[(size_t)blk * NB + b0] : 0;
    int v1c = (b1 < NB) ? histB[(size_t)blk * NB + b1] : 0;
    ps[t] = v0c + v1c;
    __syncthreads();
    for (int o = 1; o < 256; o <<= 1) {
        int v = (t >= o) ? ps[t - o] : 0;
        __syncthreads();
        ps[t] += v;
        __syncthreads();
    }
    int excl = ps[t] - v0c - v1c;
    tloff[b0] = excl;
    tloff[b1] = excl + v0c;
    tcnt[b0] = 0; tcnt[b1] = 0;
    if (b0 < NB) wadj[b0] = bbase[b0] + cursorT[(size_t)b0 * PBLK2 + blk] - excl;
    if (b1 < NB) wadj[b1] = bbase[b1] + cursorT[(size_t)b1 * PBLK2 + blk] - (excl + v0c);
    __syncthreads();
    for (int i = lo + t; i < hi; i += 256) {
        int d = dst[i], s = src[i];
        int b = d >> 8;
        int pos = tloff[b] + atomicAdd(&tcnt[b], 1);
        stage[pos] = ((d & 255) << 17) | s;
        sbkt[pos] = (unsigned short)b;
    }
    __syncthreads();
    for (int i = t; i < cnt; i += 256) {
        int b = sbkt[i];
        part[wadj[b] + i] = stage[i];
    }
}

// one block/bucket: LDS count -> scan -> rowst/dis/v0 -> place csr
__global__ __launch_bounds__(512) void k_build(const int* __restrict__ bbase,
                                               const int* __restrict__ part,
                                               const float* __restrict__ x,
                                               int* __restrict__ rowst,
                                               float* __restrict__ dis,
                                               float* __restrict__ v0,
                                               int* __restrict__ csr,
                                               int N) {
    __shared__ int dcnt[256], doff[256];
    int b = blockIdx.x, t = threadIdx.x;
    int lo = bbase[b], hi = bbase[b + 1];
    if (t < 256) dcnt[t] = 0;
    __syncthreads();
    for (int i = lo + t; i < hi; i += 512)
        atomicAdd(&dcnt[part[i] >> 17], 1);
    __syncthreads();
    int own = 0;
    if (t < 256) { own = dcnt[t]; doff[t] = own; }
    __syncthreads();
    for (int o = 1; o < 256; o <<= 1) {
        int v = 0;
        if (t < 256 && t >= o) v = doff[t - o];
        __syncthreads();
        if (t < 256) doff[t] += v;
        __syncthreads();
    }
    if (t < 256) {
        int excl = doff[t] - own;
        int node = (b << 8) + t;
        if (node < N) {
            rowst[node] = lo + excl;
            float dn = rsqrtf((float)own + 1.0f);
            dis[node] = dn;
            float2 xv = *reinterpret_cast<const float2*>(x + 2 * node);
            *reinterpret_cast<float2*>(v0 + 2 * node) = make_float2(dn * xv.x, dn * xv.y);
        }
        dcnt[t] = excl;
    }
    __syncthreads();
    for (int i = lo + t; i < hi; i += 512) {
        int pv = part[i];
        int slot = atomicAdd(&dcnt[pv >> 17], 1);
        csr[lo + slot] = pv & 0x1FFFF;
    }
}

// ==== gather kernels (8 lanes/node, 8-deep idx prefetch + batched values) ====

// pass 1: gather 2-wide v0; epilogue applies W0,b0 then W1 -> u1 (8-wide)
__global__ __launch_bounds__(NT) void k_gL1(const int* __restrict__ rowst,
                                            const int* __restrict__ csr,
                                            const float* __restrict__ dis,
                                            const float* __restrict__ v0,
                                            const float* __restrict__ W0,
                                            const float* __restrict__ b0,
                                            const float* __restrict__ W1,
                                            float* __restrict__ un, int N) {
    int g = blockIdx.x * NT + threadIdx.x;
    int n = g >> 3, sub = g & 7;
    if (n >= N) return;
    int base = rowst[n], end = rowst[n + 1];
    int i = base + sub;
    float ax = 0.0f, ay = 0.0f;
    int idx[8];
#pragma unroll
    for (int k = 0; k < 8; ++k) {
        int j = i + 8 * k;
        idx[k] = (j < end) ? csr[j] : -1;
    }
    float2 vv[8];
#pragma unroll
    for (int k = 0; k < 8; ++k) {
        int s = idx[k] >= 0 ? idx[k] : n;
        vv[k] = *reinterpret_cast<const float2*>(v0 + 2 * s);
    }
#pragma unroll
    for (int k = 0; k < 8; ++k) {
        if (idx[k] >= 0) { ax += vv[k].x; ay += vv[k].y; }
    }
    for (int j = base + 64 + sub; j < end; j += 8) {
        int s = csr[j];
        float2 p = *reinterpret_cast<const float2*>(v0 + 2 * s);
        ax += p.x; ay += p.y;
    }
    ax += __shfl_xor(ax, 1, 64); ax += __shfl_xor(ax, 2, 64); ax += __shfl_xor(ax, 4, 64);
    ay += __shfl_xor(ay, 1, 64); ay += __shfl_xor(ay, 2, 64); ay += __shfl_xor(ay, 4, 64);
    float2 sv = *reinterpret_cast<const float2*>(v0 + 2 * n);
    ax += sv.x; ay += sv.y;
    float dn = dis[n];
    float gg = dn * (ax * W0[sub] + ay * W0[8 + sub]) + b0[sub];
    float h = gg > 0.0f ? gg : expm1f(gg);
    int lb = (threadIdx.x & 63) & ~7;
    float o = 0.0f;
#pragma unroll
    for (int k = 0; k < 8; ++k) o += __shfl(h, lb + k, 64) * W1[k * 8 + sub];
    un[8 * n + sub] = dn * o;
}

// mid pass: gather 8-wide u; reduce-scatter; epilogue bias+elu+W -> un
__global__ __launch_bounds__(NT) void k_gL8(const int* __restrict__ rowst,
                                            const int* __restrict__ csr,
                                            const float* __restrict__ dis,
                                            const float* __restrict__ u,
                                            const float* __restrict__ b,
                                            const float* __restrict__ W,
                                            float* __restrict__ un, int N) {
    int g = blockIdx.x * NT + threadIdx.x;
    int n = g >> 3, sub = g & 7;
    if (n >= N) return;
    int base = rowst[n], end = rowst[n + 1];
    int i = base + sub;
    float a[8];
#pragma unroll
    for (int k = 0; k < 8; ++k) a[k] = 0.0f;
    int idx[8];
#pragma unroll
    for (int k = 0; k < 8; ++k) {
        int j = i + 8 * k;
        idx[k] = (j < end) ? csr[j] : -1;
    }
    float4 v0r[8], v1r[8];
#pragma unroll
    for (int k = 0; k < 8; ++k) {
        int s = idx[k] >= 0 ? idx[k] : n;
        v0r[k] = *reinterpret_cast<const float4*>(u + 8 * s);
        v1r[k] = *reinterpret_cast<const float4*>(u + 8 * s + 4);
    }
#pragma unroll
    for (int k = 0; k < 8; ++k) {
        if (idx[k] >= 0) {
            a[0] += v0r[k].x; a[1] += v0r[k].y; a[2] += v0r[k].z; a[3] += v0r[k].w;
            a[4] += v1r[k].x; a[5] += v1r[k].y; a[6] += v1r[k].z; a[7] += v1r[k].w;
        }
    }
    for (int j = base + 64 + sub; j < end; j += 8) {
        int s = csr[j];
        float4 p0 = *reinterpret_cast<const float4*>(u + 8 * s);
        float4 p1 = *reinterpret_cast<const float4*>(u + 8 * s + 4);
        a[0] += p0.x; a[1] += p0.y; a[2] += p0.z; a[3] += p0.w;
        a[4] += p1.x; a[5] += p1.y; a[6] += p1.z; a[7] += p1.w;
    }
    // reduce-scatter butterfly: lane sub ends owning feature sub in a[0]
    int c4 = sub & 4, c2 = sub & 2, c1 = sub & 1;
#pragma unroll
    for (int j = 0; j < 4; ++j) {
        float send = c4 ? a[j] : a[j + 4];
        float recv = __shfl_xor(send, 4, 64);
        a[j] = (c4 ? a[j + 4] : a[j]) + recv;
    }
#pragma unroll
    for (int j = 0; j < 2; ++j) {
        float send = c2 ? a[j] : a[j + 2];
        float recv = __shfl_xor(send, 2, 64);
        a[j] = (c2 ? a[j + 2] : a[j]) + recv;
    }
    {
        float send = c1 ? a[0] : a[1];
        float recv = __shfl_xor(send, 1, 64);
        a[0] = (c1 ? a[1] : a[0]) + recv;
    }
    float dn = dis[n];
    float va = a[0] + u[8 * n + sub];
    float gg = va * dn + b[sub];
    float h = gg > 0.0f ? gg : expm1f(gg);
    int lb = (threadIdx.x & 63) & ~7;
    float o = 0.0f;
#pragma unroll
    for (int k = 0; k < 8; ++k) o += __shfl(h, lb + k, 64) * W[k * 8 + sub];
    un[8 * n + sub] = dn * o;
}

// head pass: gather 8-wide u3; epilogue b3+elu then Wv/Wp -> uH (2-wide)
__global__ __launch_bounds__(NT) void k_gHead(const int* __restrict__ rowst,
                                              const int* __restrict__ csr,
                                              const float* __restrict__ dis,
                                              const float* __restrict__ u,
                                              const float* __restrict__ b,
                                              const float* __restrict__ Wv,
                                              const float* __restrict__ Wp,
                                              float* __restrict__ uH, int N) {
    int g = blockIdx.x * NT + threadIdx.x;
    int n = g >> 3, sub = g & 7;
    if (n >= N) return;
    int base = rowst[n], end = rowst[n + 1];
    int i = base + sub;
    float a[8];
#pragma unroll
    for (int k = 0; k < 8; ++k) a[k] = 0.0f;
    int idx[8];
#pragma unroll
    for (int k = 0; k < 8; ++k) {
        int j = i + 8 * k;
        idx[k] = (j < end) ? csr[j] : -1;
    }
    float4 v0r[8], v1r[8];
#pragma unroll
    for (int k = 0; k < 8; ++k) {
        int s = idx[k] >= 0 ? idx[k] : n;
        v0r[k] = *reinterpret_cast<const float4*>(u + 8 * s);
        v1r[k] = *reinterpret_cast<const float4*>(u + 8 * s + 4);
    }
#pragma unroll
    for (int k = 0; k < 8; ++k) {
        if (idx[k] >= 0) {
            a[0] += v0r[k].x; a[1] += v0r[k].y; a[2] += v0r[k].z; a[3] += v0r[k].w;
            a[4] += v1r[k].x; a[5] += v1r[k].y; a[6] += v1r[k].z; a[7] += v1r[k].w;
        }
    }
    for (int j = base + 64 + sub; j < end; j += 8) {
        int s = csr[j];
        float4 p0 = *reinterpret_cast<const float4*>(u + 8 * s);
        float4 p1 = *reinterpret_cast<const float4*>(u + 8 * s + 4);
        a[0] += p0.x; a[1] += p0.y; a[2] += p0.z; a[3] += p0.w;
        a[4] += p1.x; a[5] += p1.y; a[6] += p1.z; a[7] += p1.w;
    }
    int c4 = sub & 4, c2 = sub & 2, c1 = sub & 1;
#pragma unroll
    for (int j = 0; j < 4; ++j) {
        float send = c4 ? a[j] : a[j + 4];
        float recv = __shfl_xor(send, 4, 64);
        a[j] = (c4 ? a[j + 4] : a[j]) + recv;
    }
#pragma unroll
    for (int j = 0; j < 2; ++j) {
        float send = c2 ? a[j] : a[j + 2];
        float recv = __shfl_xor(send, 2, 64);
        a[j] = (c2 ? a[j + 2] : a[j]) + recv;
    }
    {
        float send = c1 ? a[0] : a[1];
        float recv = __shfl_xor(send, 1, 64);
        a[0] = (c1 ? a[1] : a[0]) + recv;
    }
    float dn = dis[n];
    float va = a[0] + u[8 * n + sub];
    float gg = va * dn + b[sub];
    float h = gg > 0.0f ? gg : expm1f(gg);
    float tv = h * Wv[sub];
    float tp = h * Wp[sub];
    tv += __shfl_xor(tv, 1, 64); tv += __shfl_xor(tv, 2, 64); tv += __shfl_xor(tv, 4, 64);
    tp += __shfl_xor(tp, 1, 64); tp += __shfl_xor(tp, 2, 64); tp += __shfl_xor(tp, 4, 64);
    if (sub == 0)
        *reinterpret_cast<float2*>(uH + 2 * n) = make_float2(dn * tv, dn * tp);
}

// final: gather 2-wide uH -> proba out + value reduce
__global__ __launch_bounds__(NT) void k_g2F(const int* __restrict__ rowst,
                                            const int* __restrict__ csr,
                                            const float* __restrict__ dis,
                                            const float* __restrict__ uH,
                                            const float* __restrict__ bp,
                                            float* __restrict__ out,
                                            float* __restrict__ vsum, int N) {
    int g = blockIdx.x * NT + threadIdx.x;
    int n = g >> 3, sub = g & 7;
    bool valid = n < N;
    float av = 0.0f, ap = 0.0f;
    if (valid) {
        int base = rowst[n], end = rowst[n + 1];
        int i = base + sub;
        int idx[8];
#pragma unroll
        for (int k = 0; k < 8; ++k) {
            int j = i + 8 * k;
            idx[k] = (j < end) ? csr[j] : -1;
        }
        float2 vv[8];
#pragma unroll
        for (int k = 0; k < 8; ++k) {
            int s = idx[k] >= 0 ? idx[k] : n;
            vv[k] = *reinterpret_cast<const float2*>(uH + 2 * s);
        }
#pragma unroll
        for (int k = 0; k < 8; ++k) {
            if (idx[k] >= 0) { av += vv[k].x; ap += vv[k].y; }
        }
        for (int j = base + 64 + sub; j < end; j += 8) {
            int s = csr[j];
            float2 p = *reinterpret_cast<const float2*>(uH + 2 * s);
            av += p.x; ap += p.y;
        }
    }
    av += __shfl_xor(av, 1, 64); av += __shfl_xor(av, 2, 64); av += __shfl_xor(av, 4, 64);
    ap += __shfl_xor(ap, 1, 64); ap += __shfl_xor(ap, 2, 64); ap += __shfl_xor(ap, 4, 64);
    float contrib = 0.0f;
    if (valid && sub == 0) {
        float2 selfv = *reinterpret_cast<const float2*>(uH + 2 * n);
        av += selfv.x; ap += selfv.y;
        float dn = dis[n];
        out[n] = ap * dn + bp[0];
        contrib = av * dn;
    }
#pragma unroll
    for (int o = 32; o > 0; o >>= 1) contrib += __shfl_down(contrib, o, 64);
    __shared__ float sred[NT / 64];
    if ((threadIdx.x & 63) == 0) sred[threadIdx.x >> 6] = contrib;
    __syncthreads();
    if (threadIdx.x == 0) {
        float bsum = 0.0f;
#pragma unroll
        for (int k = 0; k < NT / 64; ++k) bsum += sred[k];
        atomicAdd(vsum, bsum);
    }
}

__global__ void k_final(const float* __restrict__ vsum,
                        const float* __restrict__ bv,
                        float* __restrict__ out, int N) {
    out[0] = vsum[0] * (1.0f / (float)N) + bv[0];
}

// ============== fallback: two-pass exact-CSR build ==============

__global__ __launch_bounds__(NT) void k_count(const int* __restrict__ dst,
                                              int* __restrict__ deg, int E) {
    int e = blockIdx.x * NT + threadIdx.x;
    if (e < E) atomicAdd(&deg[dst[e]], 1);
}

__global__ __launch_bounds__(NT) void k_scanA(const int* __restrict__ deg,
                                              int* __restrict__ partial, int N) {
    int t = threadIdx.x;
    int base = blockIdx.x * CHUNK + t * 4;
    int s = 0;
#pragma unroll
    for (int j = 0; j < 4; ++j) { int i = base + j; if (i < N) s += deg[i]; }
    __shared__ int red[NT];
    red[t] = s; __syncthreads();
    for (int o = NT / 2; o > 0; o >>= 1) {
        if (t < o) red[t] += red[t + o];
        __syncthreads();
    }
    if (t == 0) partial[blockIdx.x] = red[0];
}

__global__ void k_scanB(const int* __restrict__ partial, int* __restrict__ chunkoff,
                        int* __restrict__ rowst, int nblk, int N) {
    if (threadIdx.x == 0) {
        int off = 0;
        for (int b = 0; b < nblk; ++b) { chunkoff[b] = off; off += partial[b]; }
        rowst[N] = off;
    }
}

__global__ __launch_bounds__(NT) void k_scanC(const int* __restrict__ deg,
                                              const int* __restrict__ chunkoff,
                                              int* __restrict__ rowst,
                                              float* __restrict__ dis, int N) {
    int t = threadIdx.x;
    int base = blockIdx.x * CHUNK + t * 4;
    int v[4]; int tsum = 0;
#pragma unroll
    for (int j = 0; j < 4; ++j) { int i = base + j; v[j] = (i < N) ? deg[i] : 0; tsum += v[j]; }
    __shared__ int ss[NT];
    ss[t] = tsum; __syncthreads();
    for (int o = 1; o < NT; o <<= 1) {
        int x = (t >= o) ? ss[t - o] : 0;
        __syncthreads();
        ss[t] += x;
        __syncthreads();
    }
    int run = ss[t] - tsum + chunkoff[blockIdx.x];
#pragma unroll
    for (int j = 0; j < 4; ++j) {
        int i = base + j;
        if (i < N) { rowst[i] = run; dis[i] = rsqrtf((float)v[j] + 1.0f); run += v[j]; }
    }
}

__global__ __launch_bounds__(NT) void k_fill(const int* __restrict__ src,
                                             const int* __restrict__ dst,
                                             const int* __restrict__ rowst,
                                             int* __restrict__ deg,
                                             int* __restrict__ csr, int E) {
    int e = blockIdx.x * NT + threadIdx.x;
    if (e >= E) return;
    int s = src[e], d = dst[e];
    int old = atomicSub(&deg[d], 1);
    csr[rowst[d] + old - 1] = s;
}

__global__ __launch_bounds__(NT) void k_v0(const float* __restrict__ x,
                                           const float* __restrict__ dis,
                                           float* __restrict__ v0, int N) {
    int n = blockIdx.x * NT + threadIdx.x;
    if (n >= N) return;
    float dn = dis[n];
    float2 xv = *reinterpret_cast<const float2*>(x + 2 * n);
    *reinterpret_cast<float2*>(v0 + 2 * n) = make_float2(dn * xv.x, dn * xv.y);
}

// ================================ launch ================================

extern "C" void kernel_launch(void* const* d_in, const int* in_sizes, int n_in,
                              void* d_out, int out_size, void* d_ws, size_t ws_size,
                              hipStream_t stream) {
    const float* x  = (const float*)d_in[0];
    const int* ei   = (const int*)d_in[1];
    const float* W0 = (const float*)d_in[2];
    const float* b0 = (const float*)d_in[3];
    const float* W1 = (const float*)d_in[4];
    const float* b1 = (const float*)d_in[5];
    const float* W2 = (const float*)d_in[6];
    const float* b2 = (const float*)d_in[7];
    const float* W3 = (const float*)d_in[8];
    const float* b3 = (const float*)d_in[9];
    const float* Wv = (const float*)d_in[10];
    const float* bv = (const float*)d_in[11];
    const float* Wp = (const float*)d_in[12];
    const float* bp = (const float*)d_in[13];
    float* out = (float*)d_out;

    int N = in_sizes[0] / 2;
    int E = in_sizes[1] / 2;
    const int* src = ei;
    const int* dst = ei + E;
    int NB = (N + 255) >> 8;
    int NP = (N + 3) & ~3;
    int EP = (E + 3) & ~3;
    int chunkP = (E + PBLK2 - 1) / PBLK2;

    size_t needP = ((size_t)22 * NP + 2 * (size_t)EP + 1044) * 4;
    bool histFits = (size_t)2 * PBLK2 * NB <= (size_t)E;

    if (N <= 131072 && NB <= 512 && ws_size >= needP && histFits && chunkP <= PTILE) {
        int* tot    = (int*)d_ws;                   // 512
        int* bbase  = tot + 512;                    // 520 (NB+1 used)
        float* vsum = (float*)(bbase + 520);        // 8
        int* rowst  = (int*)(vsum + 8);             // NP+4 (N+1 used)
        float* dis  = (float*)(rowst + NP + 4);     // NP
        float* v0   = dis + NP;                     // 2NP
        float* uA   = v0 + (size_t)2 * NP;          // 8NP
        float* uB   = uA + (size_t)8 * NP;          // 8NP
        float* uH   = uB + (size_t)8 * NP;          // 2NP
        int* part   = (int*)(uH + (size_t)2 * NP);  // EP
        int* csr    = part + (size_t)EP;            // EP
        int* histB   = csr;                         // scratch inside csr
        int* cursorT = csr + (size_t)PBLK2 * NB;

        hipMemsetAsync(vsum, 0, 4, stream);

        k_histB<<<PBLK2, 256, 0, stream>>>(dst, histB, E, NB);
        k_scanB2<<<NB, 256, 0, stream>>>(histB, cursorT, tot, NB, PBLK2);
        k_bscan<<<1, 512, 0, stream>>>(tot, bbase, rowst, NB, N, E);
        k_partF<<<PBLK2, 256, 0, stream>>>(src, dst, bbase, histB, cursorT, part, E, NB);
        k_build<<<NB, 512, 0, stream>>>(bbase, part, x, rowst, dis, v0, csr, N);

        k_gL1<<<nbi(8LL * N), NT, 0, stream>>>(rowst, csr, dis, v0, W0, b0, W1, uA, N);
        k_gL8<<<nbi(8LL * N), NT, 0, stream>>>(rowst, csr, dis, uA, b1, W2, uB, N);
        k_gL8<<<nbi(8LL * N), NT, 0, stream>>>(rowst, csr, dis, uB, b2, W3, uA, N);
        k_gHead<<<nbi(8LL * N), NT, 0, stream>>>(rowst, csr, dis, uA, b3, Wv, Wp, uH, N);
        k_g2F<<<nbi(8LL * N), NT, 0, stream>>>(rowst, csr, dis, uH, bp, out, vsum, N);
        k_final<<<1, 1, 0, stream>>>(vsum, bv, out + N, N);
    } else {
        // ---- fallback: two-pass exact CSR, same gather kernels ----
        int nblk = (N + CHUNK - 1) / CHUNK;
        int* deg      = (int*)d_ws;                 // N
        int* rowst    = deg + N;                    // N+1
        int* chunkoff = rowst + N + 1;              // nblk
        int* partial  = chunkoff + nblk;            // nblk
        float* dis    = (float*)(partial + nblk);   // N
        float* vsum   = dis + N;                    // 8
        float* v0     = vsum + 8;                   // 2N
        float* uA     = v0 + (size_t)2 * N;         // 8N
        float* uB     = uA + (size_t)8 * N;         // 8N
        float* uH     = uB + (size_t)8 * N;         // 2N
        int* csr      = (int*)(uH + (size_t)2 * N); // E

        hipMemsetAsync(deg, 0, (size_t)N * 4, stream);
        hipMemsetAsync(vsum, 0, 4, stream);

        k_count<<<nbi(E), NT, 0, stream>>>(dst, deg, E);
        k_scanA<<<nblk, NT, 0, stream>>>(deg, partial, N);
        k_scanB<<<1, 64, 0, stream>>>(partial, chunkoff, rowst, nblk, N);
        k_scanC<<<nblk, NT, 0, stream>>>(deg, chunkoff, rowst, dis, N);
        k_fill<<<nbi(E), NT, 0, stream>>>(src, dst, rowst, deg, csr, E);
        k_v0<<<nbi(N), NT, 0, stream>>>(x, dis, v0, N);

        k_gL1<<<nbi(8LL * N), NT, 0, stream>>>(rowst, csr, dis, v0, W0, b0, W1, uA, N);
        k_gL8<<<nbi(8LL * N), NT, 0, stream>>>(rowst, csr, dis, uA, b1, W2, uB, N);
        k_gL8<<<nbi(8LL * N), NT, 0, stream>>>(rowst, csr, dis, uB, b2, W3, uA, N);
        k_gHead<<<nbi(8LL * N), NT, 0, stream>>>(rowst, csr, dis, uA, b3, Wv, Wp, uH, N);
        k_g2F<<<nbi(8LL * N), NT, 0, stream>>>(rowst, csr, dis, uH, bp, out, vsum, N);
        k_final<<<1, 1, 0, stream>>>(vsum, bv, out + N, N);
    }
}